// Round 1
// baseline (332.280 us; speedup 1.0000x reference)
//
#include <hip/hip_runtime.h>

#define N_NODES 50000
#define N_EDGES 800000
#define IN_CH 128
#define HID_CH 256
#define OUT_CH 128

constexpr int TOTAL_E = N_EDGES + N_NODES;   // edges + self loops
constexpr int SCAN_BLK = 1024;
constexpr int NB_SCAN = (N_NODES + SCAN_BLK - 1) / SCAN_BLK;  // 49

// ---------------- CSR construction ----------------

__global__ void k_init(int* __restrict__ deg, int* __restrict__ cursor) {
    int i = blockIdx.x * blockDim.x + threadIdx.x;
    if (i < N_NODES) { deg[i] = 1; cursor[i] = 0; }   // 1 = self loop
}

__global__ void k_hist(const int* __restrict__ dst, int* __restrict__ deg) {
    int e = blockIdx.x * blockDim.x + threadIdx.x;
    if (e < N_EDGES) atomicAdd(&deg[dst[e]], 1);
}

__global__ void k_dis(const int* __restrict__ deg, float* __restrict__ dis) {
    int i = blockIdx.x * blockDim.x + threadIdx.x;
    if (i < N_NODES) dis[i] = rsqrtf((float)deg[i]);  // deg >= 1 always
}

__global__ void k_scan1(const int* __restrict__ cnt, int* __restrict__ incl,
                        int* __restrict__ part) {
    __shared__ int s[SCAN_BLK];
    int t = threadIdx.x;
    int i = blockIdx.x * SCAN_BLK + t;
    int v = (i < N_NODES) ? cnt[i] : 0;
    s[t] = v; __syncthreads();
    for (int o = 1; o < SCAN_BLK; o <<= 1) {
        int a = (t >= o) ? s[t - o] : 0;
        __syncthreads();
        s[t] += a;
        __syncthreads();
    }
    if (i < N_NODES) incl[i] = s[t];
    if (t == SCAN_BLK - 1) part[blockIdx.x] = s[t];
}

__global__ void k_scan2(int* __restrict__ part) {
    int t = threadIdx.x;   // single wave of 64, NB_SCAN=49 <= 64
    int v = (t < NB_SCAN) ? part[t] : 0;
    int orig = v;
    for (int o = 1; o < 64; o <<= 1) {
        int u = __shfl_up(v, o);
        if (t >= o) v += u;
    }
    if (t < NB_SCAN) part[t] = v - orig;   // exclusive
}

__global__ void k_scan3(const int* __restrict__ incl, const int* __restrict__ cnt,
                        const int* __restrict__ part, int* __restrict__ off) {
    int i = blockIdx.x * blockDim.x + threadIdx.x;
    if (i < N_NODES) off[i] = part[i >> 10] + incl[i] - cnt[i];
}

__global__ void k_fill(const int* __restrict__ src, const int* __restrict__ dst,
                       const float* __restrict__ dis, const int* __restrict__ off,
                       int* __restrict__ cursor, int* __restrict__ col,
                       float* __restrict__ wgt) {
    int e = blockIdx.x * blockDim.x + threadIdx.x;
    if (e >= TOTAL_E) return;
    int s, d;
    if (e < N_EDGES) { s = src[e]; d = dst[e]; }
    else             { s = d = e - N_EDGES; }          // self loop
    int pos = off[d] + atomicAdd(&cursor[d], 1);
    col[pos] = s;
    wgt[pos] = dis[s] * dis[d];
}

// ---------------- aggregation: out[v] = sum_e w_e * feat[col_e]  (F = 128) ----------------

template<bool BIAS, bool RELU>
__global__ void k_agg(const float* __restrict__ feat, const int* __restrict__ col,
                      const float* __restrict__ wgt, const int* __restrict__ off,
                      const int* __restrict__ cnt, const float* __restrict__ bias,
                      float* __restrict__ out) {
    __shared__ int   cl[128];
    __shared__ float wl[128];
    int v = blockIdx.x;
    int t = threadIdx.x;           // 128 threads = channel
    int start = off[v];
    int len   = cnt[v];
    float acc = 0.f;
    for (int base = 0; base < len; base += 128) {
        int n = min(128, len - base);
        if (t < n) {
            cl[t] = col[start + base + t];
            wl[t] = wgt[start + base + t];
        }
        __syncthreads();
        for (int j = 0; j < n; ++j)
            acc += wl[j] * feat[(size_t)cl[j] * 128 + t];
        __syncthreads();
    }
    if (BIAS) acc += bias[t];
    if (RELU) acc = fmaxf(acc, 0.f);
    out[(size_t)v * 128 + t] = acc;
}

// ---------------- fp32 GEMM: out[M,NC] = A[M,K] @ W[K,NC] (+bias, relu) ----------------

template<int K, int NC, bool BIAS, bool RELU>
__global__ __launch_bounds__(256)
void k_gemm(const float* __restrict__ A, const float* __restrict__ W,
            const float* __restrict__ bias, float* __restrict__ out, int M) {
    constexpr int KC = 32;           // K-chunk staged in LDS
    constexpr int TM = 64;           // rows per block
    constexpr int CG = NC / 4;       // col groups (4 cols/thread)
    constexpr int RG = 256 / CG;     // row groups
    constexpr int RPT = TM / RG;     // rows per thread
    __shared__ float Wl[KC * NC];
    __shared__ float Xl[TM * KC];
    int t = threadIdx.x;
    int m0 = blockIdx.x * TM;
    int cg = t % CG, rg = t / CG;

    float4 acc[RPT];
    #pragma unroll
    for (int r = 0; r < RPT; ++r) acc[r] = make_float4(0.f, 0.f, 0.f, 0.f);

    for (int kk = 0; kk < K; kk += KC) {
        // stage W chunk (contiguous rows kk..kk+KC)
        {
            const float4* Wg = (const float4*)(W + (size_t)kk * NC);
            float4* Wd = (float4*)Wl;
            #pragma unroll
            for (int i = t; i < KC * NC / 4; i += 256) Wd[i] = Wg[i];
        }
        // stage X tile [TM][KC]
        {
            float4* Xd = (float4*)Xl;
            #pragma unroll
            for (int i = t; i < TM * KC / 4; i += 256) {
                int r = i / (KC / 4);
                int c = (i % (KC / 4)) * 4;
                int row = m0 + r;
                float4 v = make_float4(0.f, 0.f, 0.f, 0.f);
                if (row < M) v = *(const float4*)(A + (size_t)row * K + kk + c);
                Xd[i] = v;
            }
        }
        __syncthreads();
        #pragma unroll 4
        for (int kc = 0; kc < KC; ++kc) {
            float4 w = *(const float4*)&Wl[kc * NC + cg * 4];
            #pragma unroll
            for (int r = 0; r < RPT; ++r) {
                float xv = Xl[(rg * RPT + r) * KC + kc];
                acc[r].x = fmaf(xv, w.x, acc[r].x);
                acc[r].y = fmaf(xv, w.y, acc[r].y);
                acc[r].z = fmaf(xv, w.z, acc[r].z);
                acc[r].w = fmaf(xv, w.w, acc[r].w);
            }
        }
        __syncthreads();
    }

    float4 bv = make_float4(0.f, 0.f, 0.f, 0.f);
    if (BIAS) bv = *(const float4*)&bias[cg * 4];
    #pragma unroll
    for (int r = 0; r < RPT; ++r) {
        int row = m0 + rg * RPT + r;
        if (row >= M) break;
        float4 o = acc[r];
        if (BIAS) { o.x += bv.x; o.y += bv.y; o.z += bv.z; o.w += bv.w; }
        if (RELU) {
            o.x = fmaxf(o.x, 0.f); o.y = fmaxf(o.y, 0.f);
            o.z = fmaxf(o.z, 0.f); o.w = fmaxf(o.w, 0.f);
        }
        *(float4*)(out + (size_t)row * NC + cg * 4) = o;
    }
}

// ---------------- launch ----------------

extern "C" void kernel_launch(void* const* d_in, const int* in_sizes, int n_in,
                              void* d_out, int out_size, void* d_ws, size_t ws_size,
                              hipStream_t stream) {
    const float* x   = (const float*)d_in[0];
    const int*   ei  = (const int*)d_in[1];
    const int*   src = ei;
    const int*   dst = ei + N_EDGES;
    const float* W1  = (const float*)d_in[3];
    const float* b1  = (const float*)d_in[4];
    const float* W2  = (const float*)d_in[5];
    const float* b2  = (const float*)d_in[6];
    float* out = (float*)d_out;

    char* ws = (char*)d_ws;
    size_t o = 0;
    auto carve = [&](size_t bytes) {
        void* p = ws + o;
        o += (bytes + 255) & ~(size_t)255;
        return p;
    };
    int*   deg    = (int*)  carve(N_NODES * 4);
    int*   cursor = (int*)  carve(N_NODES * 4);
    float* dis    = (float*)carve(N_NODES * 4);
    int*   incl   = (int*)  carve(N_NODES * 4);
    int*   part   = (int*)  carve(64 * 4);
    int*   off    = (int*)  carve(N_NODES * 4);
    int*   col    = (int*)  carve((size_t)TOTAL_E * 4);
    float* wgt    = (float*)carve((size_t)TOTAL_E * 4);
    float* agg1   = (float*)carve((size_t)N_NODES * 128 * 4);  // also reused as t2
    float* h1     = (float*)carve((size_t)N_NODES * 256 * 4);
    float* t2     = agg1;  // agg1 is dead after gemm1 -> reuse for gemm2 output

    const int B = 256;
    k_init <<<(N_NODES + B - 1) / B, B, 0, stream>>>(deg, cursor);
    k_hist <<<(N_EDGES + B - 1) / B, B, 0, stream>>>(dst, deg);
    k_dis  <<<(N_NODES + B - 1) / B, B, 0, stream>>>(deg, dis);
    k_scan1<<<NB_SCAN, SCAN_BLK, 0, stream>>>(deg, incl, part);
    k_scan2<<<1, 64, 0, stream>>>(part);
    k_scan3<<<(N_NODES + B - 1) / B, B, 0, stream>>>(incl, deg, part, off);
    k_fill <<<(TOTAL_E + B - 1) / B, B, 0, stream>>>(src, dst, dis, off, cursor, col, wgt);

    // layer 1: agg1 = A x ; h1 = relu(agg1 @ W1 + b1)
    k_agg<false, false><<<N_NODES, 128, 0, stream>>>(x, col, wgt, off, deg, nullptr, agg1);
    k_gemm<IN_CH, HID_CH, true, true><<<(N_NODES + 63) / 64, 256, 0, stream>>>(agg1, W1, b1, h1, N_NODES);

    // layer 2: t2 = h1 @ W2 ; out = relu(A t2 + b2)
    k_gemm<HID_CH, OUT_CH, false, false><<<(N_NODES + 63) / 64, 256, 0, stream>>>(h1, W2, nullptr, t2, N_NODES);
    k_agg<true, true><<<N_NODES, 128, 0, stream>>>(t2, col, wgt, off, deg, b2, out);
}

// Round 2
// 311.928 us; speedup vs baseline: 1.0652x; 1.0652x over previous
//
#include <hip/hip_runtime.h>

#define N_NODES 50000
#define N_EDGES 800000
#define IN_CH 128
#define HID_CH 256
#define OUT_CH 128

constexpr int TOTAL_E = N_EDGES + N_NODES;   // edges + self loops
constexpr int SCAN_BLK = 1024;
constexpr int NB_SCAN = (N_NODES + SCAN_BLK - 1) / SCAN_BLK;  // 49

typedef __attribute__((ext_vector_type(8))) short bf16x8;
typedef __attribute__((ext_vector_type(4))) float f32x4;
typedef __attribute__((ext_vector_type(4))) unsigned int u32x4;

// ---------------- bf16 split helpers ----------------

__device__ __forceinline__ unsigned int bf16rn(float x) {
    unsigned int u = __float_as_uint(x);
    return (u + 0x7fffu + ((u >> 16) & 1u)) >> 16;   // round-to-nearest-even
}

// pack two floats into one dword of 2 bf16 (hi part) and residual (lo part)
__device__ __forceinline__ void split2(float x0, float x1,
                                       unsigned int& h, unsigned int& l) {
    unsigned int h0 = bf16rn(x0), h1 = bf16rn(x1);
    float f0 = __uint_as_float(h0 << 16), f1 = __uint_as_float(h1 << 16);
    unsigned int l0 = bf16rn(x0 - f0), l1 = bf16rn(x1 - f1);
    h = h0 | (h1 << 16);
    l = l0 | (l1 << 16);
}

__device__ __forceinline__ bf16x8 asbf(u32x4 v) {
    return __builtin_bit_cast(bf16x8, v);
}

// ---------------- CSR construction ----------------

__global__ void k_init(int* __restrict__ deg, int* __restrict__ cursor) {
    int i = blockIdx.x * blockDim.x + threadIdx.x;
    if (i < N_NODES) { deg[i] = 1; cursor[i] = 0; }   // 1 = self loop
}

__global__ void k_hist(const int* __restrict__ dst, int* __restrict__ deg) {
    int e = blockIdx.x * blockDim.x + threadIdx.x;
    if (e < N_EDGES) atomicAdd(&deg[dst[e]], 1);
}

__global__ void k_dis(const int* __restrict__ deg, float* __restrict__ dis) {
    int i = blockIdx.x * blockDim.x + threadIdx.x;
    if (i < N_NODES) dis[i] = rsqrtf((float)deg[i]);  // deg >= 1 always
}

__global__ void k_scan1(const int* __restrict__ cnt, int* __restrict__ incl,
                        int* __restrict__ part) {
    __shared__ int s[SCAN_BLK];
    int t = threadIdx.x;
    int i = blockIdx.x * SCAN_BLK + t;
    int v = (i < N_NODES) ? cnt[i] : 0;
    s[t] = v; __syncthreads();
    for (int o = 1; o < SCAN_BLK; o <<= 1) {
        int a = (t >= o) ? s[t - o] : 0;
        __syncthreads();
        s[t] += a;
        __syncthreads();
    }
    if (i < N_NODES) incl[i] = s[t];
    if (t == SCAN_BLK - 1) part[blockIdx.x] = s[t];
}

__global__ void k_scan2(int* __restrict__ part) {
    int t = threadIdx.x;   // single wave of 64, NB_SCAN=49 <= 64
    int v = (t < NB_SCAN) ? part[t] : 0;
    int orig = v;
    for (int o = 1; o < 64; o <<= 1) {
        int u = __shfl_up(v, o);
        if (t >= o) v += u;
    }
    if (t < NB_SCAN) part[t] = v - orig;   // exclusive
}

__global__ void k_scan3(const int* __restrict__ incl, const int* __restrict__ cnt,
                        const int* __restrict__ part, int* __restrict__ off) {
    int i = blockIdx.x * blockDim.x + threadIdx.x;
    if (i < N_NODES) off[i] = part[i >> 10] + incl[i] - cnt[i];
}

__global__ void k_fill(const int* __restrict__ src, const int* __restrict__ dst,
                       const float* __restrict__ dis, const int* __restrict__ off,
                       int* __restrict__ cursor, int* __restrict__ col,
                       float* __restrict__ wgt) {
    int e = blockIdx.x * blockDim.x + threadIdx.x;
    if (e >= TOTAL_E) return;
    int s, d;
    if (e < N_EDGES) { s = src[e]; d = dst[e]; }
    else             { s = d = e - N_EDGES; }          // self loop
    int pos = off[d] + atomicAdd(&cursor[d], 1);
    col[pos] = s;
    wgt[pos] = dis[s] * dis[d];
}

// ---- aggregation: out[v] = sum_e w_e * feat[col_e]  (F = 128, one wave/node) ----

template<bool BIAS, bool RELU>
__global__ __launch_bounds__(64)
void k_agg(const float* __restrict__ feat, const int* __restrict__ col,
           const float* __restrict__ wgt, const int* __restrict__ off,
           const int* __restrict__ cnt, const float* __restrict__ bias,
           float* __restrict__ out) {
    __shared__ int   cl[64];
    __shared__ float wl[64];
    int v = blockIdx.x;
    int t = threadIdx.x;           // 64 threads, 2 channels each (float2)
    int start = off[v];
    int len   = cnt[v];
    float2 acc = make_float2(0.f, 0.f);
    for (int base = 0; base < len; base += 64) {
        int n = min(64, len - base);
        if (t < n) {
            cl[t] = col[start + base + t];
            wl[t] = wgt[start + base + t];
        }
        __syncthreads();
        for (int j = 0; j < n; ++j) {
            float w = wl[j];
            float2 f = *(const float2*)&feat[(size_t)cl[j] * 128 + t * 2];
            acc.x = fmaf(w, f.x, acc.x);
            acc.y = fmaf(w, f.y, acc.y);
        }
        __syncthreads();
    }
    if (BIAS) {
        float2 b = *(const float2*)&bias[t * 2];
        acc.x += b.x; acc.y += b.y;
    }
    if (RELU) { acc.x = fmaxf(acc.x, 0.f); acc.y = fmaxf(acc.y, 0.f); }
    *(float2*)&out[(size_t)v * 128 + t * 2] = acc;
}

// ---- W split into MFMA-fragment-ordered bf16 hi/lo --------------------------
// Fragment layout (16x16x32 bf16): B col n = lane&15, k = (lane>>4)*8 + i.
// Wf[((kt*NT+nt)*2 + h)*64 + lane] = u32x4 of 8 bf16 (h=0 hi, h=1 lo)

template<int K, int NC>
__global__ void k_wsplit(const float* __restrict__ W, u32x4* __restrict__ Wf) {
    constexpr int KT = K / 32, NT = NC / 16;
    int tid = blockIdx.x * blockDim.x + threadIdx.x;
    if (tid >= KT * NT * 64) return;
    int lane = tid & 63;
    int ntk  = tid >> 6;           // kt*NT + nt
    int kt = ntk / NT, nt = ntk % NT;
    int kb = kt * 32 + (lane >> 4) * 8;
    int n  = nt * 16 + (lane & 15);
    unsigned int hh[4], ll[4];
    #pragma unroll
    for (int j = 0; j < 4; ++j) {
        float x0 = W[(size_t)(kb + 2 * j) * NC + n];
        float x1 = W[(size_t)(kb + 2 * j + 1) * NC + n];
        split2(x0, x1, hh[j], ll[j]);
    }
    Wf[(size_t)(ntk * 2 + 0) * 64 + lane] = (u32x4){hh[0], hh[1], hh[2], hh[3]};
    Wf[(size_t)(ntk * 2 + 1) * 64 + lane] = (u32x4){ll[0], ll[1], ll[2], ll[3]};
}

// ---- MFMA GEMM: out[M,NC] = A[M,K] @ W[K,NC] (+bias, relu), split-bf16 3-pass ----
// One wave per 32 rows. A fp32 -> hi/lo bf16 in registers; B frags from global (L2).

template<int K, int NC, bool BIAS, bool RELU>
__global__ __launch_bounds__(64)
void k_gemm_mfma(const float* __restrict__ A, const u32x4* __restrict__ Wf,
                 const float* __restrict__ bias, float* __restrict__ out, int M) {
    constexpr int KT = K / 32, NT = NC / 16;
    int lane = threadIdx.x;
    int lq = lane >> 4;            // 0..3
    int lr = lane & 15;
    int kq = lq * 8;
    int rbase = blockIdx.x * 32;

    // load + split A: rows rbase+lr (set 0) and rbase+16+lr (set 1)
    bf16x8 ah[2][KT], al[2][KT];
    #pragma unroll
    for (int s = 0; s < 2; ++s) {
        int row = rbase + s * 16 + lr;
        const float* Ar = A + (size_t)min(row, M - 1) * K;
        #pragma unroll
        for (int kt = 0; kt < KT; ++kt) {
            float4 u = *(const float4*)(Ar + kt * 32 + kq);
            float4 v = *(const float4*)(Ar + kt * 32 + kq + 4);
            unsigned int h0, l0, h1, l1, h2, l2, h3, l3;
            split2(u.x, u.y, h0, l0); split2(u.z, u.w, h1, l1);
            split2(v.x, v.y, h2, l2); split2(v.z, v.w, h3, l3);
            ah[s][kt] = asbf((u32x4){h0, h1, h2, h3});
            al[s][kt] = asbf((u32x4){l0, l1, l2, l3});
        }
    }

    f32x4 acc[2][NT];
    #pragma unroll
    for (int s = 0; s < 2; ++s)
        #pragma unroll
        for (int nt = 0; nt < NT; ++nt)
            acc[s][nt] = (f32x4){0.f, 0.f, 0.f, 0.f};

    #pragma unroll
    for (int nt = 0; nt < NT; ++nt) {
        #pragma unroll
        for (int kt = 0; kt < KT; ++kt) {
            bf16x8 bh = asbf(Wf[(size_t)((kt * NT + nt) * 2 + 0) * 64 + lane]);
            bf16x8 bl = asbf(Wf[(size_t)((kt * NT + nt) * 2 + 1) * 64 + lane]);
            // D = Ah*Wh + Al*Wh + Ah*Wl  (drop Al*Wl ~ 2^-18)
            acc[0][nt] = __builtin_amdgcn_mfma_f32_16x16x32_bf16(ah[0][kt], bh, acc[0][nt], 0, 0, 0);
            acc[1][nt] = __builtin_amdgcn_mfma_f32_16x16x32_bf16(ah[1][kt], bh, acc[1][nt], 0, 0, 0);
            acc[0][nt] = __builtin_amdgcn_mfma_f32_16x16x32_bf16(al[0][kt], bh, acc[0][nt], 0, 0, 0);
            acc[1][nt] = __builtin_amdgcn_mfma_f32_16x16x32_bf16(al[1][kt], bh, acc[1][nt], 0, 0, 0);
            acc[0][nt] = __builtin_amdgcn_mfma_f32_16x16x32_bf16(ah[0][kt], bl, acc[0][nt], 0, 0, 0);
            acc[1][nt] = __builtin_amdgcn_mfma_f32_16x16x32_bf16(ah[1][kt], bl, acc[1][nt], 0, 0, 0);
        }
    }

    // epilogue: D col = lane&15, row = (lane>>4)*4 + j
    #pragma unroll
    for (int nt = 0; nt < NT; ++nt) {
        int colg = nt * 16 + lr;
        float bv = BIAS ? bias[colg] : 0.f;
        #pragma unroll
        for (int s = 0; s < 2; ++s) {
            #pragma unroll
            for (int j = 0; j < 4; ++j) {
                int row = rbase + s * 16 + lq * 4 + j;
                if (row < M) {
                    float o = acc[s][nt][j] + bv;
                    if (RELU) o = fmaxf(o, 0.f);
                    out[(size_t)row * NC + colg] = o;
                }
            }
        }
    }
}

// ---------------- launch ----------------

extern "C" void kernel_launch(void* const* d_in, const int* in_sizes, int n_in,
                              void* d_out, int out_size, void* d_ws, size_t ws_size,
                              hipStream_t stream) {
    const float* x   = (const float*)d_in[0];
    const int*   ei  = (const int*)d_in[1];
    const int*   src = ei;
    const int*   dst = ei + N_EDGES;
    const float* W1  = (const float*)d_in[3];
    const float* b1  = (const float*)d_in[4];
    const float* W2  = (const float*)d_in[5];
    const float* b2  = (const float*)d_in[6];
    float* out = (float*)d_out;

    char* ws = (char*)d_ws;
    size_t o = 0;
    auto carve = [&](size_t bytes) {
        void* p = ws + o;
        o += (bytes + 255) & ~(size_t)255;
        return p;
    };
    int*   deg    = (int*)  carve(N_NODES * 4);
    int*   cursor = (int*)  carve(N_NODES * 4);
    float* dis    = (float*)carve(N_NODES * 4);
    int*   incl   = (int*)  carve(N_NODES * 4);
    int*   part   = (int*)  carve(64 * 4);
    int*   off    = (int*)  carve(N_NODES * 4);
    int*   col    = (int*)  carve((size_t)TOTAL_E * 4);
    float* wgt    = (float*)carve((size_t)TOTAL_E * 4);
    float* agg1   = (float*)carve((size_t)N_NODES * 128 * 4);  // reused as t2
    float* h1     = (float*)carve((size_t)N_NODES * 256 * 4);
    u32x4* Wf1    = (u32x4*)carve((size_t)(IN_CH/32) * (HID_CH/16) * 2 * 64 * 16);
    u32x4* Wf2    = (u32x4*)carve((size_t)(HID_CH/32) * (OUT_CH/16) * 2 * 64 * 16);
    float* t2     = agg1;  // agg1 dead after gemm1 -> reuse for gemm2 output

    const int B = 256;
    k_init <<<(N_NODES + B - 1) / B, B, 0, stream>>>(deg, cursor);
    k_hist <<<(N_EDGES + B - 1) / B, B, 0, stream>>>(dst, deg);
    k_dis  <<<(N_NODES + B - 1) / B, B, 0, stream>>>(deg, dis);
    k_scan1<<<NB_SCAN, SCAN_BLK, 0, stream>>>(deg, incl, part);
    k_scan2<<<1, 64, 0, stream>>>(part);
    k_scan3<<<(N_NODES + B - 1) / B, B, 0, stream>>>(incl, deg, part, off);
    k_fill <<<(TOTAL_E + B - 1) / B, B, 0, stream>>>(src, dst, dis, off, cursor, col, wgt);

    // W fragment prep (small, L2-resident afterwards)
    k_wsplit<IN_CH,  HID_CH><<<( (IN_CH/32)*(HID_CH/16)*64 + B - 1) / B, B, 0, stream>>>(W1, Wf1);
    k_wsplit<HID_CH, OUT_CH><<<( (HID_CH/32)*(OUT_CH/16)*64 + B - 1) / B, B, 0, stream>>>(W2, Wf2);

    // layer 1: agg1 = A x ; h1 = relu(agg1 @ W1 + b1)
    k_agg<false, false><<<N_NODES, 64, 0, stream>>>(x, col, wgt, off, deg, nullptr, agg1);
    k_gemm_mfma<IN_CH, HID_CH, true, true>
        <<<(N_NODES + 31) / 32, 64, 0, stream>>>(agg1, Wf1, b1, h1, N_NODES);

    // layer 2: t2 = h1 @ W2 ; out = relu(A t2 + b2)
    k_gemm_mfma<HID_CH, OUT_CH, false, false>
        <<<(N_NODES + 31) / 32, 64, 0, stream>>>(h1, Wf2, nullptr, t2, N_NODES);
    k_agg<true, true><<<N_NODES, 64, 0, stream>>>(t2, col, wgt, off, deg, b2, out);
}

// Round 3
// 280.651 us; speedup vs baseline: 1.1840x; 1.1114x over previous
//
#include <hip/hip_runtime.h>

#define N_NODES 50000
#define N_EDGES 800000
#define IN_CH 128
#define HID_CH 256
#define OUT_CH 128

constexpr int TOTAL_E = N_EDGES + N_NODES;   // edges + self loops
constexpr int SCAN_BLK = 1024;
constexpr int NB_SCAN = (N_NODES + SCAN_BLK - 1) / SCAN_BLK;  // 49

typedef __attribute__((ext_vector_type(8))) short bf16x8;
typedef __attribute__((ext_vector_type(4))) float f32x4;
typedef __attribute__((ext_vector_type(4))) unsigned int u32x4;

// ---------------- bf16 split helpers ----------------

__device__ __forceinline__ unsigned int bf16rn(float x) {
    unsigned int u = __float_as_uint(x);
    return (u + 0x7fffu + ((u >> 16) & 1u)) >> 16;   // round-to-nearest-even
}

// pack two floats into one dword of 2 bf16 (hi part) and residual (lo part)
__device__ __forceinline__ void split2(float x0, float x1,
                                       unsigned int& h, unsigned int& l) {
    unsigned int h0 = bf16rn(x0), h1 = bf16rn(x1);
    float f0 = __uint_as_float(h0 << 16), f1 = __uint_as_float(h1 << 16);
    unsigned int l0 = bf16rn(x0 - f0), l1 = bf16rn(x1 - f1);
    h = h0 | (h1 << 16);
    l = l0 | (l1 << 16);
}

__device__ __forceinline__ bf16x8 asbf(u32x4 v) {
    return __builtin_bit_cast(bf16x8, v);
}

// ---------------- CSR construction ----------------

__global__ void k_init(int* __restrict__ deg, int* __restrict__ cursor) {
    int i = blockIdx.x * blockDim.x + threadIdx.x;
    if (i < N_NODES) { deg[i] = 1; cursor[i] = 0; }   // 1 = self loop
}

__global__ void k_hist(const int* __restrict__ dst, int* __restrict__ deg) {
    int e = blockIdx.x * blockDim.x + threadIdx.x;
    if (e < N_EDGES) atomicAdd(&deg[dst[e]], 1);
}

__global__ void k_scan1(const int* __restrict__ cnt, int* __restrict__ incl,
                        int* __restrict__ part) {
    __shared__ int s[SCAN_BLK];
    int t = threadIdx.x;
    int i = blockIdx.x * SCAN_BLK + t;
    int v = (i < N_NODES) ? cnt[i] : 0;
    s[t] = v; __syncthreads();
    for (int o = 1; o < SCAN_BLK; o <<= 1) {
        int a = (t >= o) ? s[t - o] : 0;
        __syncthreads();
        s[t] += a;
        __syncthreads();
    }
    if (i < N_NODES) incl[i] = s[t];
    if (t == SCAN_BLK - 1) part[blockIdx.x] = s[t];
}

__global__ void k_scan2(int* __restrict__ part) {
    int t = threadIdx.x;   // single wave of 64, NB_SCAN=49 <= 64
    int v = (t < NB_SCAN) ? part[t] : 0;
    int orig = v;
    for (int o = 1; o < 64; o <<= 1) {
        int u = __shfl_up(v, o);
        if (t >= o) v += u;
    }
    if (t < NB_SCAN) part[t] = v - orig;   // exclusive
}

// also computes dis = rsqrt(deg)
__global__ void k_scan3(const int* __restrict__ incl, const int* __restrict__ cnt,
                        const int* __restrict__ part, int* __restrict__ off,
                        float* __restrict__ dis) {
    int i = blockIdx.x * blockDim.x + threadIdx.x;
    if (i < N_NODES) {
        off[i] = part[i >> 10] + incl[i] - cnt[i];
        dis[i] = rsqrtf((float)cnt[i]);   // deg >= 1 always
    }
}

__global__ void k_fill(const int* __restrict__ src, const int* __restrict__ dst,
                       const float* __restrict__ dis, const int* __restrict__ off,
                       int* __restrict__ cursor, int* __restrict__ col,
                       float* __restrict__ wgt) {
    int e = blockIdx.x * blockDim.x + threadIdx.x;
    if (e >= TOTAL_E) return;
    int s, d;
    if (e < N_EDGES) { s = src[e]; d = dst[e]; }
    else             { s = d = e - N_EDGES; }          // self loop
    int pos = off[d] + atomicAdd(&cursor[d], 1);
    col[pos] = s;
    wgt[pos] = dis[s] * dis[d];
}

// ---- aggregation: out[v] = sum_e w_e * feat[col_e]  (F = 128) -----------------
// 4 waves/block, one node per wave, no LDS, no barriers; shfl-broadcast edges;
// unroll x4 for memory-level parallelism.

template<bool BIAS, bool RELU>
__global__ __launch_bounds__(256)
void k_agg(const float* __restrict__ feat, const int* __restrict__ col,
           const float* __restrict__ wgt, const int* __restrict__ off,
           const int* __restrict__ cnt, const float* __restrict__ bias,
           float* __restrict__ out) {
    int wid  = threadIdx.x >> 6;
    int lane = threadIdx.x & 63;
    int v = blockIdx.x * 4 + wid;          // grid is exactly N_NODES/4
    int start = off[v];
    int len   = cnt[v];
    float2 acc = make_float2(0.f, 0.f);
    for (int base = 0; base < len; base += 64) {
        int n = min(64, len - base);
        int   cv = 0;
        float wv = 0.f;
        if (lane < n) {
            cv = col[start + base + lane];
            wv = wgt[start + base + lane];
        }
        int j = 0;
        for (; j + 4 <= n; j += 4) {
            int   c0 = __shfl(cv, j),     c1 = __shfl(cv, j + 1);
            int   c2 = __shfl(cv, j + 2), c3 = __shfl(cv, j + 3);
            float w0 = __shfl(wv, j),     w1 = __shfl(wv, j + 1);
            float w2 = __shfl(wv, j + 2), w3 = __shfl(wv, j + 3);
            float2 f0 = *(const float2*)&feat[(size_t)c0 * 128 + lane * 2];
            float2 f1 = *(const float2*)&feat[(size_t)c1 * 128 + lane * 2];
            float2 f2 = *(const float2*)&feat[(size_t)c2 * 128 + lane * 2];
            float2 f3 = *(const float2*)&feat[(size_t)c3 * 128 + lane * 2];
            acc.x = fmaf(w0, f0.x, acc.x); acc.y = fmaf(w0, f0.y, acc.y);
            acc.x = fmaf(w1, f1.x, acc.x); acc.y = fmaf(w1, f1.y, acc.y);
            acc.x = fmaf(w2, f2.x, acc.x); acc.y = fmaf(w2, f2.y, acc.y);
            acc.x = fmaf(w3, f3.x, acc.x); acc.y = fmaf(w3, f3.y, acc.y);
        }
        for (; j < n; ++j) {
            int   c = __shfl(cv, j);
            float w = __shfl(wv, j);
            float2 f = *(const float2*)&feat[(size_t)c * 128 + lane * 2];
            acc.x = fmaf(w, f.x, acc.x);
            acc.y = fmaf(w, f.y, acc.y);
        }
    }
    if (BIAS) {
        float2 b = *(const float2*)&bias[lane * 2];
        acc.x += b.x; acc.y += b.y;
    }
    if (RELU) { acc.x = fmaxf(acc.x, 0.f); acc.y = fmaxf(acc.y, 0.f); }
    *(float2*)&out[(size_t)v * 128 + lane * 2] = acc;
}

// ---- W split into MFMA-fragment-ordered bf16 hi/lo --------------------------
// Fragment layout (16x16x32 bf16): B col n = lane&15, k = (lane>>4)*8 + i.
// Wf[((kt*NT+nt)*2 + h)*64 + lane] = u32x4 of 8 bf16 (h=0 hi, h=1 lo)

template<int K, int NC>
__global__ void k_wsplit(const float* __restrict__ W, u32x4* __restrict__ Wf) {
    constexpr int KT = K / 32, NT = NC / 16;
    int tid = blockIdx.x * blockDim.x + threadIdx.x;
    if (tid >= KT * NT * 64) return;
    int lane = tid & 63;
    int ntk  = tid >> 6;           // kt*NT + nt
    int kt = ntk / NT, nt = ntk % NT;
    int kb = kt * 32 + (lane >> 4) * 8;
    int n  = nt * 16 + (lane & 15);
    unsigned int hh[4], ll[4];
    #pragma unroll
    for (int j = 0; j < 4; ++j) {
        float x0 = W[(size_t)(kb + 2 * j) * NC + n];
        float x1 = W[(size_t)(kb + 2 * j + 1) * NC + n];
        split2(x0, x1, hh[j], ll[j]);
    }
    Wf[(size_t)(ntk * 2 + 0) * 64 + lane] = (u32x4){hh[0], hh[1], hh[2], hh[3]};
    Wf[(size_t)(ntk * 2 + 1) * 64 + lane] = (u32x4){ll[0], ll[1], ll[2], ll[3]};
}

// ---- MFMA GEMM: out[M,NC] = A[M,K] @ W[K,NC] (+bias, relu), split-bf16 3-pass ----
// 2 waves/block; each wave owns 32 rows x (NC/2) cols. kt-outer loop keeps only
// the current K-chunk's A fragments live (low VGPR -> high occupancy).

template<int K, int NC, bool BIAS, bool RELU>
__global__ __launch_bounds__(128)
void k_gemm_mfma(const float* __restrict__ A, const u32x4* __restrict__ Wf,
                 const float* __restrict__ bias, float* __restrict__ out, int M) {
    constexpr int KT = K / 32, NT = NC / 16, NTW = NT / 2;
    int lane = threadIdx.x & 63;
    int wid  = threadIdx.x >> 6;
    int lq = lane >> 4;            // 0..3
    int lr = lane & 15;
    int kq = lq * 8;
    int rbase = blockIdx.x * 32;
    int nt0 = wid * NTW;

    f32x4 acc[2][NTW];
    #pragma unroll
    for (int s = 0; s < 2; ++s)
        #pragma unroll
        for (int t = 0; t < NTW; ++t)
            acc[s][t] = (f32x4){0.f, 0.f, 0.f, 0.f};

    for (int kt = 0; kt < KT; ++kt) {
        // load + split this K-chunk of A: rows rbase+s*16+lr, cols kt*32+kq..+8
        bf16x8 ah[2], al[2];
        #pragma unroll
        for (int s = 0; s < 2; ++s) {
            int row = rbase + s * 16 + lr;
            const float* Ar = A + (size_t)min(row, M - 1) * K + kt * 32 + kq;
            float4 u = *(const float4*)Ar;
            float4 v = *(const float4*)(Ar + 4);
            unsigned int h0, l0, h1, l1, h2, l2, h3, l3;
            split2(u.x, u.y, h0, l0); split2(u.z, u.w, h1, l1);
            split2(v.x, v.y, h2, l2); split2(v.z, v.w, h3, l3);
            ah[s] = asbf((u32x4){h0, h1, h2, h3});
            al[s] = asbf((u32x4){l0, l1, l2, l3});
        }
        #pragma unroll
        for (int t = 0; t < NTW; ++t) {
            int nt = nt0 + t;
            const u32x4* wp = Wf + (size_t)((kt * NT + nt) * 2) * 64 + lane;
            bf16x8 bh = asbf(wp[0]);
            bf16x8 bl = asbf(wp[64]);
            // D = Ah*Wh + Al*Wh + Ah*Wl  (drop Al*Wl ~ 2^-18)
            acc[0][t] = __builtin_amdgcn_mfma_f32_16x16x32_bf16(ah[0], bh, acc[0][t], 0, 0, 0);
            acc[1][t] = __builtin_amdgcn_mfma_f32_16x16x32_bf16(ah[1], bh, acc[1][t], 0, 0, 0);
            acc[0][t] = __builtin_amdgcn_mfma_f32_16x16x32_bf16(al[0], bh, acc[0][t], 0, 0, 0);
            acc[1][t] = __builtin_amdgcn_mfma_f32_16x16x32_bf16(al[1], bh, acc[1][t], 0, 0, 0);
            acc[0][t] = __builtin_amdgcn_mfma_f32_16x16x32_bf16(ah[0], bl, acc[0][t], 0, 0, 0);
            acc[1][t] = __builtin_amdgcn_mfma_f32_16x16x32_bf16(ah[1], bl, acc[1][t], 0, 0, 0);
        }
    }

    // epilogue: D col = lane&15, row = (lane>>4)*4 + j
    #pragma unroll
    for (int t = 0; t < NTW; ++t) {
        int colg = (nt0 + t) * 16 + lr;
        float bv = BIAS ? bias[colg] : 0.f;
        #pragma unroll
        for (int s = 0; s < 2; ++s) {
            #pragma unroll
            for (int j = 0; j < 4; ++j) {
                int row = rbase + s * 16 + lq * 4 + j;
                if (row < M) {
                    float o = acc[s][t][j] + bv;
                    if (RELU) o = fmaxf(o, 0.f);
                    out[(size_t)row * NC + colg] = o;
                }
            }
        }
    }
}

// ---------------- launch ----------------

extern "C" void kernel_launch(void* const* d_in, const int* in_sizes, int n_in,
                              void* d_out, int out_size, void* d_ws, size_t ws_size,
                              hipStream_t stream) {
    const float* x   = (const float*)d_in[0];
    const int*   ei  = (const int*)d_in[1];
    const int*   src = ei;
    const int*   dst = ei + N_EDGES;
    const float* W1  = (const float*)d_in[3];
    const float* b1  = (const float*)d_in[4];
    const float* W2  = (const float*)d_in[5];
    const float* b2  = (const float*)d_in[6];
    float* out = (float*)d_out;

    char* ws = (char*)d_ws;
    size_t o = 0;
    auto carve = [&](size_t bytes) {
        void* p = ws + o;
        o += (bytes + 255) & ~(size_t)255;
        return p;
    };
    int*   deg    = (int*)  carve(N_NODES * 4);
    int*   cursor = (int*)  carve(N_NODES * 4);
    float* dis    = (float*)carve(N_NODES * 4);
    int*   incl   = (int*)  carve(N_NODES * 4);
    int*   part   = (int*)  carve(64 * 4);
    int*   off    = (int*)  carve(N_NODES * 4);
    int*   col    = (int*)  carve((size_t)TOTAL_E * 4);
    float* wgt    = (float*)carve((size_t)TOTAL_E * 4);
    float* agg1   = (float*)carve((size_t)N_NODES * 128 * 4);  // reused as t2
    float* h1     = (float*)carve((size_t)N_NODES * 256 * 4);
    u32x4* Wf1    = (u32x4*)carve((size_t)(IN_CH/32) * (HID_CH/16) * 2 * 64 * 16);
    u32x4* Wf2    = (u32x4*)carve((size_t)(HID_CH/32) * (OUT_CH/16) * 2 * 64 * 16);
    float* t2     = agg1;  // agg1 dead after gemm1 -> reuse for gemm2 output

    const int B = 256;
    k_init <<<(N_NODES + B - 1) / B, B, 0, stream>>>(deg, cursor);
    k_hist <<<(N_EDGES + B - 1) / B, B, 0, stream>>>(dst, deg);
    k_scan1<<<NB_SCAN, SCAN_BLK, 0, stream>>>(deg, incl, part);
    k_scan2<<<1, 64, 0, stream>>>(part);
    k_scan3<<<(N_NODES + B - 1) / B, B, 0, stream>>>(incl, deg, part, off, dis);
    k_fill <<<(TOTAL_E + B - 1) / B, B, 0, stream>>>(src, dst, dis, off, cursor, col, wgt);

    // W fragment prep (small, L2-resident afterwards)
    k_wsplit<IN_CH,  HID_CH><<<( (IN_CH/32)*(HID_CH/16)*64 + B - 1) / B, B, 0, stream>>>(W1, Wf1);
    k_wsplit<HID_CH, OUT_CH><<<( (HID_CH/32)*(OUT_CH/16)*64 + B - 1) / B, B, 0, stream>>>(W2, Wf2);

    // layer 1: agg1 = A x ; h1 = relu(agg1 @ W1 + b1)
    k_agg<false, false><<<N_NODES / 4, 256, 0, stream>>>(x, col, wgt, off, deg, nullptr, agg1);
    k_gemm_mfma<IN_CH, HID_CH, true, true>
        <<<(N_NODES + 31) / 32, 128, 0, stream>>>(agg1, Wf1, b1, h1, N_NODES);

    // layer 2: t2 = h1 @ W2 ; out = relu(A t2 + b2)
    k_gemm_mfma<HID_CH, OUT_CH, false, false>
        <<<(N_NODES + 31) / 32, 128, 0, stream>>>(h1, Wf2, nullptr, t2, N_NODES);
    k_agg<true, true><<<N_NODES / 4, 256, 0, stream>>>(t2, col, wgt, off, deg, b2, out);
}

// Round 4
// 227.759 us; speedup vs baseline: 1.4589x; 1.2322x over previous
//
#include <hip/hip_runtime.h>

#define N_NODES 50000
#define N_EDGES 800000
#define IN_CH 128
#define HID_CH 256
#define OUT_CH 128

constexpr int TOTAL_E = N_EDGES + N_NODES;   // edges + self loops
constexpr int SCAN_BLK = 1024;
constexpr int NB_SCAN = (N_NODES + SCAN_BLK - 1) / SCAN_BLK;  // 49

typedef __attribute__((ext_vector_type(8))) short bf16x8;
typedef __attribute__((ext_vector_type(4))) float f32x4;
typedef __attribute__((ext_vector_type(4))) unsigned int u32x4;

// ---------------- bf16 helpers ----------------

__device__ __forceinline__ unsigned int bf16rn(float x) {
    unsigned int u = __float_as_uint(x);
    return (u + 0x7fffu + ((u >> 16) & 1u)) >> 16;   // round-to-nearest-even
}

__device__ __forceinline__ void split2(float x0, float x1,
                                       unsigned int& h, unsigned int& l) {
    unsigned int h0 = bf16rn(x0), h1 = bf16rn(x1);
    float f0 = __uint_as_float(h0 << 16), f1 = __uint_as_float(h1 << 16);
    unsigned int l0 = bf16rn(x0 - f0), l1 = bf16rn(x1 - f1);
    h = h0 | (h1 << 16);
    l = l0 | (l1 << 16);
}

__device__ __forceinline__ bf16x8 asbf(u32x4 v) {
    return __builtin_bit_cast(bf16x8, v);
}

// ---------------- fp32 -> bf16 row copy ----------------

__global__ void k_tobf(const float* __restrict__ x, unsigned short* __restrict__ xb,
                       int n8) {
    int i = blockIdx.x * blockDim.x + threadIdx.x;
    if (i >= n8) return;
    const float4* p = (const float4*)(x + (size_t)i * 8);
    float4 a = p[0], b = p[1];
    u32x4 w;
    w.x = bf16rn(a.x) | (bf16rn(a.y) << 16);
    w.y = bf16rn(a.z) | (bf16rn(a.w) << 16);
    w.z = bf16rn(b.x) | (bf16rn(b.y) << 16);
    w.w = bf16rn(b.z) | (bf16rn(b.w) << 16);
    *(u32x4*)(xb + (size_t)i * 8) = w;
}

// ---------------- CSR construction ----------------

__global__ void k_init(int* __restrict__ deg, int* __restrict__ cursor) {
    int i = blockIdx.x * blockDim.x + threadIdx.x;
    if (i < N_NODES) { deg[i] = 1; cursor[i] = 0; }   // 1 = self loop
}

__global__ void k_hist(const int* __restrict__ dst, int* __restrict__ deg) {
    int e = blockIdx.x * blockDim.x + threadIdx.x;
    if (e < N_EDGES) atomicAdd(&deg[dst[e]], 1);
}

__global__ void k_scan1(const int* __restrict__ cnt, int* __restrict__ incl,
                        int* __restrict__ part) {
    __shared__ int s[SCAN_BLK];
    int t = threadIdx.x;
    int i = blockIdx.x * SCAN_BLK + t;
    int v = (i < N_NODES) ? cnt[i] : 0;
    s[t] = v; __syncthreads();
    for (int o = 1; o < SCAN_BLK; o <<= 1) {
        int a = (t >= o) ? s[t - o] : 0;
        __syncthreads();
        s[t] += a;
        __syncthreads();
    }
    if (i < N_NODES) incl[i] = s[t];
    if (t == SCAN_BLK - 1) part[blockIdx.x] = s[t];
}

__global__ void k_scan2(int* __restrict__ part) {
    int t = threadIdx.x;   // single wave of 64, NB_SCAN=49 <= 64
    int v = (t < NB_SCAN) ? part[t] : 0;
    int orig = v;
    for (int o = 1; o < 64; o <<= 1) {
        int u = __shfl_up(v, o);
        if (t >= o) v += u;
    }
    if (t < NB_SCAN) part[t] = v - orig;   // exclusive
}

// also computes dis = rsqrt(deg)
__global__ void k_scan3(const int* __restrict__ incl, const int* __restrict__ cnt,
                        const int* __restrict__ part, int* __restrict__ off,
                        float* __restrict__ dis) {
    int i = blockIdx.x * blockDim.x + threadIdx.x;
    if (i < N_NODES) {
        off[i] = part[i >> 10] + incl[i] - cnt[i];
        dis[i] = rsqrtf((float)cnt[i]);   // deg >= 1 always
    }
}

__global__ void k_fill(const int* __restrict__ src, const int* __restrict__ dst,
                       const float* __restrict__ dis, const int* __restrict__ off,
                       int* __restrict__ cursor, int* __restrict__ col,
                       float* __restrict__ wgt) {
    int e = blockIdx.x * blockDim.x + threadIdx.x;
    if (e >= TOTAL_E) return;
    int s, d;
    if (e < N_EDGES) { s = src[e]; d = dst[e]; }
    else             { s = d = e - N_EDGES; }          // self loop
    int pos = off[d] + atomicAdd(&cursor[d], 1);
    col[pos] = s;
    wgt[pos] = dis[s] * dis[d];
}

// ---- bf16 aggregation: out[v] = sum_e w_e * featb[col_e]  (F = 128) ----------
// 4 waves/block, one node per wave. Two edges processed per step: lanes 0-31 take
// edge j, lanes 32-63 edge j+1; each lane covers 4 channels (8 B load). Cross-half
// reduce at the end via shfl_xor(32). No LDS, no barriers.

template<bool BIAS, bool RELU>
__global__ __launch_bounds__(256)
void k_agg_bf(const unsigned short* __restrict__ featb, const int* __restrict__ col,
              const float* __restrict__ wgt, const int* __restrict__ off,
              const int* __restrict__ cnt, const float* __restrict__ bias,
              float* __restrict__ out) {
    int wid  = threadIdx.x >> 6;
    int lane = threadIdx.x & 63;
    int v = blockIdx.x * 4 + wid;          // grid is exactly N_NODES/4
    int start = off[v];
    int len   = cnt[v];
    int half = lane >> 5;                  // which edge of the pair
    int q    = lane & 31;                  // channel quad: ch q*4..q*4+3
    float4 acc = make_float4(0.f, 0.f, 0.f, 0.f);
    for (int base = 0; base < len; base += 64) {
        int n = min(64, len - base);
        int   cv = 0;
        float wv = 0.f;
        if (lane < n) {
            cv = col[start + base + lane];
            wv = wgt[start + base + lane];
        }
        auto pair = [&](int j) {
            int   c = __shfl(cv, j + half);   // j+half==n on odd tail -> w=0, c=0
            float w = __shfl(wv, j + half);
            uint2 d = *(const uint2*)&featb[(size_t)c * 128 + q * 4];
            acc.x = fmaf(w, __uint_as_float(d.x << 16),         acc.x);
            acc.y = fmaf(w, __uint_as_float(d.x & 0xffff0000u), acc.y);
            acc.z = fmaf(w, __uint_as_float(d.y << 16),         acc.z);
            acc.w = fmaf(w, __uint_as_float(d.y & 0xffff0000u), acc.w);
        };
        int j = 0;
        for (; j + 8 <= n; j += 8) { pair(j); pair(j + 2); pair(j + 4); pair(j + 6); }
        for (; j < n; j += 2) pair(j);
    }
    acc.x += __shfl_xor(acc.x, 32);
    acc.y += __shfl_xor(acc.y, 32);
    acc.z += __shfl_xor(acc.z, 32);
    acc.w += __shfl_xor(acc.w, 32);
    if (half == 0) {
        float4 o = acc;
        if (BIAS) {
            float4 b = *(const float4*)&bias[q * 4];
            o.x += b.x; o.y += b.y; o.z += b.z; o.w += b.w;
        }
        if (RELU) {
            o.x = fmaxf(o.x, 0.f); o.y = fmaxf(o.y, 0.f);
            o.z = fmaxf(o.z, 0.f); o.w = fmaxf(o.w, 0.f);
        }
        *(float4*)&out[(size_t)v * 128 + q * 4] = o;
    }
}

// ---- W split into MFMA-fragment-ordered bf16 hi/lo --------------------------
// Fragment layout (16x16x32 bf16): B col n = lane&15, k = (lane>>4)*8 + i.

template<int K, int NC>
__global__ void k_wsplit(const float* __restrict__ W, u32x4* __restrict__ Wf) {
    constexpr int KT = K / 32, NT = NC / 16;
    int tid = blockIdx.x * blockDim.x + threadIdx.x;
    if (tid >= KT * NT * 64) return;
    int lane = tid & 63;
    int ntk  = tid >> 6;           // kt*NT + nt
    int kt = ntk / NT, nt = ntk % NT;
    int kb = kt * 32 + (lane >> 4) * 8;
    int n  = nt * 16 + (lane & 15);
    unsigned int hh[4], ll[4];
    #pragma unroll
    for (int j = 0; j < 4; ++j) {
        float x0 = W[(size_t)(kb + 2 * j) * NC + n];
        float x1 = W[(size_t)(kb + 2 * j + 1) * NC + n];
        split2(x0, x1, hh[j], ll[j]);
    }
    Wf[(size_t)(ntk * 2 + 0) * 64 + lane] = (u32x4){hh[0], hh[1], hh[2], hh[3]};
    Wf[(size_t)(ntk * 2 + 1) * 64 + lane] = (u32x4){ll[0], ll[1], ll[2], ll[3]};
}

// ---- MFMA GEMM: out[M,NC] = A[M,K] @ W[K,NC] (+bias, relu), split-bf16 3-pass ----
// 2 waves/block; each wave owns 32 rows x (NC/2) cols. kt-outer keeps VGPR low.
// BF16OUT: store output as bf16 (row-major ushort) instead of fp32.

template<int K, int NC, bool BIAS, bool RELU, bool BF16OUT>
__global__ __launch_bounds__(128)
void k_gemm_mfma(const float* __restrict__ A, const u32x4* __restrict__ Wf,
                 const float* __restrict__ bias, void* __restrict__ outv, int M) {
    constexpr int KT = K / 32, NT = NC / 16, NTW = NT / 2;
    int lane = threadIdx.x & 63;
    int wid  = threadIdx.x >> 6;
    int lq = lane >> 4;            // 0..3
    int lr = lane & 15;
    int kq = lq * 8;
    int rbase = blockIdx.x * 32;
    int nt0 = wid * NTW;

    f32x4 acc[2][NTW];
    #pragma unroll
    for (int s = 0; s < 2; ++s)
        #pragma unroll
        for (int t = 0; t < NTW; ++t)
            acc[s][t] = (f32x4){0.f, 0.f, 0.f, 0.f};

    for (int kt = 0; kt < KT; ++kt) {
        bf16x8 ah[2], al[2];
        #pragma unroll
        for (int s = 0; s < 2; ++s) {
            int row = rbase + s * 16 + lr;
            const float* Ar = A + (size_t)min(row, M - 1) * K + kt * 32 + kq;
            float4 u = *(const float4*)Ar;
            float4 v = *(const float4*)(Ar + 4);
            unsigned int h0, l0, h1, l1, h2, l2, h3, l3;
            split2(u.x, u.y, h0, l0); split2(u.z, u.w, h1, l1);
            split2(v.x, v.y, h2, l2); split2(v.z, v.w, h3, l3);
            ah[s] = asbf((u32x4){h0, h1, h2, h3});
            al[s] = asbf((u32x4){l0, l1, l2, l3});
        }
        #pragma unroll
        for (int t = 0; t < NTW; ++t) {
            int nt = nt0 + t;
            const u32x4* wp = Wf + (size_t)((kt * NT + nt) * 2) * 64 + lane;
            bf16x8 bh = asbf(wp[0]);
            bf16x8 bl = asbf(wp[64]);
            // D = Ah*Wh + Al*Wh + Ah*Wl  (drop Al*Wl ~ 2^-18)
            acc[0][t] = __builtin_amdgcn_mfma_f32_16x16x32_bf16(ah[0], bh, acc[0][t], 0, 0, 0);
            acc[1][t] = __builtin_amdgcn_mfma_f32_16x16x32_bf16(ah[1], bh, acc[1][t], 0, 0, 0);
            acc[0][t] = __builtin_amdgcn_mfma_f32_16x16x32_bf16(al[0], bh, acc[0][t], 0, 0, 0);
            acc[1][t] = __builtin_amdgcn_mfma_f32_16x16x32_bf16(al[1], bh, acc[1][t], 0, 0, 0);
            acc[0][t] = __builtin_amdgcn_mfma_f32_16x16x32_bf16(ah[0], bl, acc[0][t], 0, 0, 0);
            acc[1][t] = __builtin_amdgcn_mfma_f32_16x16x32_bf16(ah[1], bl, acc[1][t], 0, 0, 0);
        }
    }

    // epilogue: D col = lane&15, row = (lane>>4)*4 + j
    #pragma unroll
    for (int t = 0; t < NTW; ++t) {
        int colg = (nt0 + t) * 16 + lr;
        float bv = BIAS ? bias[colg] : 0.f;
        #pragma unroll
        for (int s = 0; s < 2; ++s) {
            #pragma unroll
            for (int j = 0; j < 4; ++j) {
                int row = rbase + s * 16 + lq * 4 + j;
                if (row < M) {
                    float o = acc[s][t][j] + bv;
                    if (RELU) o = fmaxf(o, 0.f);
                    if (BF16OUT)
                        ((unsigned short*)outv)[(size_t)row * NC + colg] = (unsigned short)bf16rn(o);
                    else
                        ((float*)outv)[(size_t)row * NC + colg] = o;
                }
            }
        }
    }
}

// ---------------- launch ----------------

extern "C" void kernel_launch(void* const* d_in, const int* in_sizes, int n_in,
                              void* d_out, int out_size, void* d_ws, size_t ws_size,
                              hipStream_t stream) {
    const float* x   = (const float*)d_in[0];
    const int*   ei  = (const int*)d_in[1];
    const int*   src = ei;
    const int*   dst = ei + N_EDGES;
    const float* W1  = (const float*)d_in[3];
    const float* b1  = (const float*)d_in[4];
    const float* W2  = (const float*)d_in[5];
    const float* b2  = (const float*)d_in[6];
    float* out = (float*)d_out;

    char* ws = (char*)d_ws;
    size_t o = 0;
    auto carve = [&](size_t bytes) {
        void* p = ws + o;
        o += (bytes + 255) & ~(size_t)255;
        return p;
    };
    int*   deg    = (int*)  carve(N_NODES * 4);
    int*   cursor = (int*)  carve(N_NODES * 4);
    float* dis    = (float*)carve(N_NODES * 4);
    int*   incl   = (int*)  carve(N_NODES * 4);
    int*   part   = (int*)  carve(64 * 4);
    int*   off    = (int*)  carve(N_NODES * 4);
    int*   col    = (int*)  carve((size_t)TOTAL_E * 4);
    float* wgt    = (float*)carve((size_t)TOTAL_E * 4);
    float* agg1   = (float*)carve((size_t)N_NODES * 128 * 4);
    float* h1     = (float*)carve((size_t)N_NODES * 256 * 4);
    u32x4* Wf1    = (u32x4*)carve((size_t)(IN_CH/32) * (HID_CH/16) * 2 * 64 * 16);
    u32x4* Wf2    = (u32x4*)carve((size_t)(HID_CH/32) * (OUT_CH/16) * 2 * 64 * 16);
    // Aliases (lifetimes verified by launch order):
    //   xb  aliases h1  : xb written first, dead after agg1; h1 written in gemm1 (after agg1)
    //   t2b aliases agg1: agg1 dead after gemm1; t2b written by gemm2, read by agg2
    unsigned short* xb  = (unsigned short*)h1;
    unsigned short* t2b = (unsigned short*)agg1;

    const int B = 256;
    k_tobf <<<(N_NODES * 128 / 8 + B - 1) / B, B, 0, stream>>>(x, xb, N_NODES * 128 / 8);
    k_init <<<(N_NODES + B - 1) / B, B, 0, stream>>>(deg, cursor);
    k_hist <<<(N_EDGES + B - 1) / B, B, 0, stream>>>(dst, deg);
    k_scan1<<<NB_SCAN, SCAN_BLK, 0, stream>>>(deg, incl, part);
    k_scan2<<<1, 64, 0, stream>>>(part);
    k_scan3<<<(N_NODES + B - 1) / B, B, 0, stream>>>(incl, deg, part, off, dis);
    k_fill <<<(TOTAL_E + B - 1) / B, B, 0, stream>>>(src, dst, dis, off, cursor, col, wgt);

    k_wsplit<IN_CH,  HID_CH><<<( (IN_CH/32)*(HID_CH/16)*64 + B - 1) / B, B, 0, stream>>>(W1, Wf1);
    k_wsplit<HID_CH, OUT_CH><<<( (HID_CH/32)*(OUT_CH/16)*64 + B - 1) / B, B, 0, stream>>>(W2, Wf2);

    // layer 1: agg1 = A xb ; h1 = relu(agg1 @ W1 + b1)   (clobbers xb, now dead)
    k_agg_bf<false, false><<<N_NODES / 4, 256, 0, stream>>>(xb, col, wgt, off, deg, nullptr, agg1);
    k_gemm_mfma<IN_CH, HID_CH, true, true, false>
        <<<(N_NODES + 31) / 32, 128, 0, stream>>>(agg1, Wf1, b1, h1, N_NODES);

    // layer 2: t2b = bf16(h1 @ W2) ; out = relu(A t2b + b2)
    k_gemm_mfma<HID_CH, OUT_CH, false, false, true>
        <<<(N_NODES + 31) / 32, 128, 0, stream>>>(h1, Wf2, nullptr, t2b, N_NODES);
    k_agg_bf<true, true><<<N_NODES / 4, 256, 0, stream>>>(t2b, col, wgt, off, deg, b2, out);
}